// Round 8
// baseline (157.033 us; speedup 1.0000x reference)
//
#include <hip/hip_runtime.h>
#include <hip/hip_bf16.h>
#include <math.h>

// Problem constants (fixed by the reference)
#define NROWS   65536          // 16*4096 flattened rows
#define DIM     64             // embedding dim
#define KCODES  1024           // num embeddings
#define RPB     64             // rows per block
#define NBLOCKS (NROWS / RPB)  // 1024 mega-kernel blocks -> 4 blocks/CU

// Queue thresholds. Filter dist error vs canonical fp32: split-2 bf16
// residuals + accumulation-order diff <= ~3e-5 realistic, 6e-5 paranoid.
// QGAP = 1.25e-4 keeps >=2x margin.
//   d2-d1 >= QGAP               -> i1 provably exact
//   d2-d1 <  QGAP <= d3-d1      -> true argmin in {i1,i2}: 2-candidate refine
//   d3-d1 <  QGAP               -> full exact scan (rare^2)
#define QGAP 1.25e-4f

typedef short short8 __attribute__((ext_vector_type(8)));   // 8 bf16 = 4 VGPR (MFMA A/B frag)
typedef float f32x4  __attribute__((ext_vector_type(4)));   // MFMA C/D frag

// Output layout (floats), reference return order:
//   out[0] loss | out[1..] quantized (N*D) | perplexity | indices (as float)
#define OUT_Q_OFF    ((size_t)1)
#define OUT_PERP_OFF ((size_t)(1 + (size_t)NROWS * DIM))
#define OUT_IDX_OFF  ((size_t)(2 + (size_t)NROWS * DIM))

// Workspace layout (bytes); zeroing done by normalize_w_kernel (stream-ordered)
#define WS_COUNTS 0                         // unsigned[1024]
#define WS_SSEC   4096                      // float   (global SSE accumulator)
#define WS_DONE   4100                      // unsigned (blocks-done counter)
#define WS_WN     8192                      // float wn[1024*64]
#define WS_SK     (WS_WN + KCODES*DIM*4)    // float sk[1024]
#define WS_WNH    (WS_SK + KCODES*4)        // ushort wnh[1024*64]
#define WS_WNL    (WS_WNH + KCODES*DIM*2)   // ushort wnl[1024*64]

__device__ __forceinline__ unsigned short bf16_rne(float f) {
  unsigned u = __float_as_uint(f);
  return (unsigned short)((u + 0x7FFFu + ((u >> 16) & 1u)) >> 16);
}
__device__ __forceinline__ float bf16f(unsigned short h) {
  return __uint_as_float(((unsigned)h) << 16);
}

// Normalize codebook + split to bf16 hi/lo + zero the mega-kernel's counters.
__global__ void __launch_bounds__(64) normalize_w_kernel(
    const float* __restrict__ w, float* __restrict__ wn, float* __restrict__ sk,
    unsigned short* __restrict__ wnh, unsigned short* __restrict__ wnl,
    unsigned* __restrict__ counts, float* __restrict__ sse_accum,
    unsigned* __restrict__ done) {
  const int k = blockIdx.x;   // one code per 64-lane wave
  const int d = threadIdx.x;
  if (d == 0) {
    counts[k] = 0u;                                   // 1024 blocks cover counts[1024]
    if (k == 0) { *sse_accum = 0.f; *done = 0u; }
  }
  float v = w[k * DIM + d];
  float ss = v * v;
  #pragma unroll
  for (int o = 32; o > 0; o >>= 1) ss += __shfl_xor(ss, o, 64);
  const float den = fmaxf(sqrtf(ss), 1e-12f);
  const float q = v / den;                 // true division: hug reference rounding
  wn[k * DIM + d] = q;
  const unsigned short h = bf16_rne(q);
  wnh[k * DIM + d] = h;
  wnl[k * DIM + d] = bf16_rne(q - bf16f(h));
  float s2 = q * q;
  #pragma unroll
  for (int o = 32; o > 0; o >>= 1) s2 += __shfl_xor(s2, o, 64);
  if (d == 0) sk[k] = s2;
}

// Mega-kernel: split-2 bf16 MFMA filter with exact fp32 top-3 tracking +
// tiered refine (2-candidate / full-scan) + bookkeeping + last-block finalize.
// Block = 256 thr (4 waves) = 64 rows (1 16-row MFMA tile per wave).
__global__ void __launch_bounds__(256) vq_mega_kernel(
    const float* __restrict__ x, const unsigned short* __restrict__ wnh,
    const unsigned short* __restrict__ wnl, const float* __restrict__ sk,
    const float* __restrict__ wn, float* __restrict__ out,
    unsigned* __restrict__ counts, float* __restrict__ sse_accum,
    unsigned* __restrict__ done) {
  // AB union: phase A: Ah=[0,2304) Al=[2304,4608) u32 (64 rows x 36 u32)
  //           phase B: buf b at b*4608: Bh=[+0,+2304) Bl=[+2304,+4608)
  __shared__ unsigned AB[9216];
  __shared__ float skb[2][64];     // staged sk per chunk
  __shared__ float c_arr[RPB];     // ||xn||^2 per row
  __shared__ float rowsse[RPB];    // per-row SSE (filter-approx; exact if refined)
  __shared__ int   ib[RPB];        // per-row final idx
  __shared__ int   qlist[RPB];     // 2-candidate refine queue: rl | i1<<6 | i2<<16
  __shared__ int   flist[RPB];     // full-scan refine queue: row_local
  __shared__ int   qn_s, fn_s;
  __shared__ int   islast;
  const int tid = threadIdx.x;
  const int lane = tid & 63, wave = tid >> 6;

  if (tid == 0) { qn_s = 0; fn_s = 0; }

  // ---- phase 1: 4 threads per row: normalize + split to bf16 hi/lo ----
  {
    const int row_l = tid >> 2;               // 0..63
    const int qr = tid & 3;                   // quarter of the row
    const size_t row = (size_t)blockIdx.x * RPB + row_l;
    const float4* xr = (const float4*)(x + row * DIM) + qr * 4;
    float4 xv[4];
    float ss = 0.f;
    #pragma unroll
    for (int i = 0; i < 4; i++) {
      xv[i] = xr[i];
      ss += xv[i].x * xv[i].x + xv[i].y * xv[i].y + xv[i].z * xv[i].z + xv[i].w * xv[i].w;
    }
    ss += __shfl_xor(ss, 1, 64); ss += __shfl_xor(ss, 2, 64);   // 4-lane row group
    const float inv = 1.0f / fmaxf(sqrtf(ss), 1e-12f);          // filter-only normalize
    float c = 0.f;
    #pragma unroll
    for (int i = 0; i < 4; i++) {
      const float a0 = xv[i].x * inv, a1 = xv[i].y * inv;
      const float a2 = xv[i].z * inv, a3 = xv[i].w * inv;
      c += a0 * a0 + a1 * a1 + a2 * a2 + a3 * a3;
      const unsigned short h0 = bf16_rne(a0), h1 = bf16_rne(a1);
      const unsigned short h2 = bf16_rne(a2), h3 = bf16_rne(a3);
      const unsigned short l0 = bf16_rne(a0 - bf16f(h0)), l1 = bf16_rne(a1 - bf16f(h1));
      const unsigned short l2 = bf16_rne(a2 - bf16f(h2)), l3 = bf16_rne(a3 - bf16f(h3));
      AB[row_l * 36 + qr * 8 + 2 * i]            = (unsigned)h0 | ((unsigned)h1 << 16);
      AB[row_l * 36 + qr * 8 + 2 * i + 1]        = (unsigned)h2 | ((unsigned)h3 << 16);
      AB[2304 + row_l * 36 + qr * 8 + 2 * i]     = (unsigned)l0 | ((unsigned)l1 << 16);
      AB[2304 + row_l * 36 + qr * 8 + 2 * i + 1] = (unsigned)l2 | ((unsigned)l3 << 16);
    }
    c += __shfl_xor(c, 1, 64); c += __shfl_xor(c, 2, 64);
    if (qr == 0) c_arr[row_l] = c;
  }
  __syncthreads();

  // ---- A fragments -> registers (A[m=lane&15][k=(lane>>4)*8+j]) ----
  short8 ah[2], al[2];
  #pragma unroll
  for (int kk = 0; kk < 2; kk++) {
    const int r = wave * 16 + (lane & 15);
    ah[kk] = *(const short8*)&AB[r * 36 + kk * 16 + (lane >> 4) * 4];
    al[kk] = *(const short8*)&AB[2304 + r * 36 + kk * 16 + (lane >> 4) * 4];
  }
  __syncthreads();   // A region now dead -> becomes B double-buffer

  // per-slot exact fp32 top-3: d1<=d2<=d3, with codes i1, i2
  float d1[4], d2[4], d3[4];
  int   i1[4], i2[4];
  #pragma unroll
  for (int s = 0; s < 4; s++) {
    d1[s] = INFINITY; d2[s] = INFINITY; d3[s] = INFINITY;
    i1[s] = 0x7FFFFFFF; i2[s] = 0x7FFFFFFF;
  }

  // stage chunk 0 into buf 0
  {
    const int code = tid >> 2, q = tid & 3;
    const float4* gh = (const float4*)(wnh + (size_t)code * DIM + q * 16);
    const float4* gl = (const float4*)(wnl + (size_t)code * DIM + q * 16);
    float4* dh = (float4*)&AB[code * 36 + q * 8];
    float4* dl = (float4*)&AB[2304 + code * 36 + q * 8];
    dh[0] = gh[0]; dh[1] = gh[1];
    dl[0] = gl[0]; dl[1] = gl[1];
    if (tid < 64) skb[0][tid] = sk[tid];
  }

  #pragma unroll 2
  for (int c = 0; c < 16; c++) {
    const int b = c & 1;
    __syncthreads();   // buf b fully staged; buf b^1 free to overwrite
    if (c < 15) {      // stage next chunk (loads fly during compute below)
      const int nb = b ^ 1;
      const int code = tid >> 2, q = tid & 3;
      const float4* gh = (const float4*)(wnh + (size_t)((c + 1) * 64 + code) * DIM + q * 16);
      const float4* gl = (const float4*)(wnl + (size_t)((c + 1) * 64 + code) * DIM + q * 16);
      float4* dh = (float4*)&AB[nb * 4608 + code * 36 + q * 8];
      float4* dl = (float4*)&AB[nb * 4608 + 2304 + code * 36 + q * 8];
      dh[0] = gh[0]; dh[1] = gh[1];
      dl[0] = gl[0]; dl[1] = gl[1];
      if (tid < 64) skb[nb][tid] = sk[(c + 1) * 64 + tid];
    }
    #pragma unroll
    for (int tt = 0; tt < 4; tt++) {
      const int cb = tt * 16 + (lane & 15);       // code within chunk (B col)
      const float skv = skb[b][cb];
      const int codev = c * 64 + cb;
      const short8 bh0 = *(const short8*)&AB[b * 4608 + cb * 36 + 0 * 16 + (lane >> 4) * 4];
      const short8 bh1 = *(const short8*)&AB[b * 4608 + cb * 36 + 1 * 16 + (lane >> 4) * 4];
      const short8 bl0 = *(const short8*)&AB[b * 4608 + 2304 + cb * 36 + 0 * 16 + (lane >> 4) * 4];
      const short8 bl1 = *(const short8*)&AB[b * 4608 + 2304 + cb * 36 + 1 * 16 + (lane >> 4) * 4];
      f32x4 acc = {0.f, 0.f, 0.f, 0.f};
      acc = __builtin_amdgcn_mfma_f32_16x16x32_bf16(ah[0], bh0, acc, 0, 0, 0);
      acc = __builtin_amdgcn_mfma_f32_16x16x32_bf16(ah[1], bh1, acc, 0, 0, 0);
      acc = __builtin_amdgcn_mfma_f32_16x16x32_bf16(al[0], bh0, acc, 0, 0, 0);
      acc = __builtin_amdgcn_mfma_f32_16x16x32_bf16(al[1], bh1, acc, 0, 0, 0);
      acc = __builtin_amdgcn_mfma_f32_16x16x32_bf16(ah[0], bl0, acc, 0, 0, 0);
      acc = __builtin_amdgcn_mfma_f32_16x16x32_bf16(ah[1], bl1, acc, 0, 0, 0);
      #pragma unroll
      for (int i = 0; i < 4; i++) {   // C layout: col=lane&15(code), row=(lane>>4)*4+i
        const float dist = fmaf(-2.0f, acc[i], skv);   // sk - 2*dot (row c uniform: dropped)
        const int s = i;
        // top-3 update (d1<=d2<=d3 invariant):
        d3[s] = __builtin_amdgcn_fmed3f(d2[s], d3[s], fmaxf(d1[s], dist));
        const bool lt2 = dist < d2[s];
        i2[s] = lt2 ? codev : i2[s];                   // provisional (fixed below if lt1)
        d2[s] = __builtin_amdgcn_fmed3f(d1[s], d2[s], dist);
        const bool lt1 = dist < d1[s];
        i2[s] = lt1 ? i1[s] : i2[s];
        i1[s] = lt1 ? codev : i1[s];
        d1[s] = lt1 ? dist : d1[s];
      }
    }
  }

  // ---- per-row top-3 reduce across the 16 lanes of each group ----
  #pragma unroll
  for (int s = 0; s < 4; s++) {
    float a1 = d1[s], a2 = d2[s], a3 = d3[s];
    int   ai = i1[s], ai2 = i2[s];
    #pragma unroll
    for (int m = 1; m < 16; m <<= 1) {
      const float p1 = __shfl_xor(a1, m, 64);
      const float p2 = __shfl_xor(a2, m, 64);
      const float p3 = __shfl_xor(a3, m, 64);
      const int   pi = __shfl_xor(ai, m, 64);
      const int   pi2 = __shfl_xor(ai2, m, 64);
      const bool take = (p1 < a1) || (p1 == a1 && pi < ai);  // first-occurrence on ties
      const float lo1 = take ? p1 : a1, lo2 = take ? p2 : a2, lo3 = take ? p3 : a3;
      const float hi1 = take ? a1 : p1, hi2 = take ? a2 : p2;
      const int   loi = take ? pi : ai, loi2 = take ? pi2 : ai2;
      const int   hii = take ? ai : pi;
      const bool c2 = hi1 < lo2;           // ties here are covered by the d3 guard
      a1 = lo1; ai = loi;
      a2 = c2 ? hi1 : lo2; ai2 = c2 ? hii : loi2;
      a3 = c2 ? fminf(lo2, hi2) : fminf(lo3, hi1);
    }
    if ((lane & 15) == 0) {
      const int row_local = wave * 16 + (lane >> 4) * 4 + s;
      ib[row_local] = ai;
      rowsse[row_local] = a1 + c_arr[row_local];   // filter-accurate ||xn-q||^2
      if (a3 - a1 < QGAP) {                        // third contender too close
        flist[atomicAdd(&fn_s, 1)] = row_local;
      } else if (a2 - a1 < QGAP) {                 // argmin provably in {i1,i2}
        qlist[atomicAdd(&qn_s, 1)] = row_local | (ai << 6) | (ai2 << 16);
      }
    }
  }
  __syncthreads();

  // ---- tier 1: 2-candidate exact refine, one THREAD per queued row ----
  const int qn = qn_s, fn = fn_s;
  if (tid < qn) {
    const int packed = qlist[tid];
    const int rl = packed & 63;
    const int c1 = (packed >> 6) & 1023, c2i = (packed >> 16) & 1023;
    const size_t row = (size_t)blockIdx.x * RPB + rl;
    const float4* xr = (const float4*)(x + row * DIM);
    float4 xv[16];
    float ss = 0.f;
    #pragma unroll
    for (int i = 0; i < 16; i++) {              // canonical serial order
      xv[i] = xr[i];
      ss += xv[i].x * xv[i].x + xv[i].y * xv[i].y + xv[i].z * xv[i].z + xv[i].w * xv[i].w;
    }
    const float den = fmaxf(sqrtf(ss), 1e-12f);
    #pragma unroll
    for (int i = 0; i < 16; i++) { xv[i].x /= den; xv[i].y /= den; xv[i].z /= den; xv[i].w /= den; }
    float cc = 0.f;
    #pragma unroll
    for (int i = 0; i < 16; i++)
      cc += xv[i].x * xv[i].x + xv[i].y * xv[i].y + xv[i].z * xv[i].z + xv[i].w * xv[i].w;
    float dd[2]; const int cand[2] = {c1, c2i};
    #pragma unroll
    for (int t = 0; t < 2; t++) {
      const float4* wr = (const float4*)(wn + (size_t)cand[t] * DIM);
      float e0 = 0.f, e1 = 0.f, e2 = 0.f, e3 = 0.f;
      #pragma unroll
      for (int i = 0; i < 16; i++) {
        const float4 wv = wr[i];
        e0 = fmaf(xv[i].x, wv.x, e0);
        e1 = fmaf(xv[i].y, wv.y, e1);
        e2 = fmaf(xv[i].z, wv.z, e2);
        e3 = fmaf(xv[i].w, wv.w, e3);
      }
      dd[t] = (cc + sk[cand[t]]) - 2.0f * ((e0 + e1) + (e2 + e3));
    }
    const bool tb = (dd[1] < dd[0]) || (dd[1] == dd[0] && c2i < c1);
    ib[rl] = tb ? c2i : c1;
    rowsse[rl] = tb ? dd[1] : dd[0];
  }

  // ---- tier 2: full exact scan, one WAVE per row (rare) ----
  for (int qi = wave; qi < fn; qi += 4) {
    const int rl = flist[qi];
    const size_t row = (size_t)blockIdx.x * RPB + rl;
    const float4* xr = (const float4*)(x + row * DIM);
    float4 xv[16];
    float ss = 0.f;
    #pragma unroll
    for (int i = 0; i < 16; i++) {
      xv[i] = xr[i];
      ss += xv[i].x * xv[i].x + xv[i].y * xv[i].y + xv[i].z * xv[i].z + xv[i].w * xv[i].w;
    }
    const float den = fmaxf(sqrtf(ss), 1e-12f);
    #pragma unroll
    for (int i = 0; i < 16; i++) { xv[i].x /= den; xv[i].y /= den; xv[i].z /= den; xv[i].w /= den; }
    float cc = 0.f;
    #pragma unroll
    for (int i = 0; i < 16; i++)
      cc += xv[i].x * xv[i].x + xv[i].y * xv[i].y + xv[i].z * xv[i].z + xv[i].w * xv[i].w;

    float best = INFINITY;
    int bidx = 0x7FFFFFFF;
    for (int j = 0; j < 16; j++) {
      const int k = j * 64 + lane;
      const float4* wr = (const float4*)(wn + (size_t)k * DIM);
      float e0 = 0.f, e1 = 0.f, e2 = 0.f, e3 = 0.f;
      #pragma unroll
      for (int i = 0; i < 16; i++) {
        const float4 wv = wr[i];
        e0 = fmaf(xv[i].x, wv.x, e0);
        e1 = fmaf(xv[i].y, wv.y, e1);
        e2 = fmaf(xv[i].z, wv.z, e2);
        e3 = fmaf(xv[i].w, wv.w, e3);
      }
      const float dot = (e0 + e1) + (e2 + e3);
      const float dist = (cc + sk[k]) - 2.0f * dot;
      if (dist < best) { best = dist; bidx = k; }   // per-lane ascending k
    }
    #pragma unroll
    for (int m = 1; m < 64; m <<= 1) {
      const float pb = __shfl_xor(best, m, 64);
      const int pi = __shfl_xor(bidx, m, 64);
      if (pb < best || (pb == best && pi < bidx)) { best = pb; bidx = pi; }  // first-occurrence
    }
    if (lane == 0) { ib[rl] = bidx; rowsse[rl] = best; }
  }
  __syncthreads();

  // ---- bookkeeping with FINAL indices ----
  if (tid < RPB) {
    const size_t row = (size_t)blockIdx.x * RPB + tid;
    const int idx = ib[tid];
    out[OUT_IDX_OFF + row] = (float)idx;
    atomicAdd(&counts[idx], 1u);
  }

  // quantized write: 64 rows x 64 elems; per wave-iter one wn row (broadcast)
  const size_t obase = OUT_Q_OFF + (size_t)blockIdx.x * (RPB * DIM);
  #pragma unroll 4
  for (int j = 0; j < 16; j++) {
    const int e = j * 256 + tid;           // e>>6 wave-uniform
    out[obase + e] = wn[(size_t)ib[e >> 6] * DIM + (e & 63)];
  }

  // block SSE reduction -> one global atomic
  __syncthreads();
  for (int s = 32; s > 0; s >>= 1) {
    if (tid < s) rowsse[tid] += rowsse[tid + s];
    __syncthreads();
  }
  if (tid == 0) atomicAdd(sse_accum, rowsse[0]);

  // ---- last-block-done finalize ----
  if (tid == 0) {
    __threadfence();                          // release: counts/sse visible device-wide
    islast = (atomicAdd(done, 1u) == NBLOCKS - 1) ? 1 : 0;
  }
  __syncthreads();
  if (islast) {
    __threadfence();                          // acquire side
    float h = 0.f;
    #pragma unroll
    for (int i = 0; i < 4; i++) {
      const float cv = (float)counts[tid * 4 + i];
      const float avg = cv * (1.0f / (float)NROWS);
      h += avg * logf(avg + 1e-10f);
    }
    #pragma unroll
    for (int o = 32; o > 0; o >>= 1) h += __shfl_xor(h, o, 64);
    __shared__ float hred[4];
    if (lane == 0) hred[wave] = h;
    __syncthreads();
    if (tid == 0) {
      const float H = -(hred[0] + hred[1] + hred[2] + hred[3]);
      const float mse = *sse_accum * (1.0f / (float)((size_t)NROWS * DIM));
      out[0] = mse + 0.25f * mse;             // == 1.25*mse in fp32
      out[OUT_PERP_OFF] = expf(H);
    }
  }
}

extern "C" void kernel_launch(void* const* d_in, const int* in_sizes, int n_in,
                              void* d_out, int out_size, void* d_ws, size_t ws_size,
                              hipStream_t stream) {
  const float* x = (const float*)d_in[0];   // [16,4096,64] fp32
  const float* w = (const float*)d_in[1];   // [1024,64] fp32
  float* out = (float*)d_out;

  char* ws = (char*)d_ws;
  unsigned* counts    = (unsigned*)(ws + WS_COUNTS);
  float* sse_accum    = (float*)(ws + WS_SSEC);
  unsigned* done      = (unsigned*)(ws + WS_DONE);
  float* wn           = (float*)(ws + WS_WN);
  float* sk           = (float*)(ws + WS_SK);
  unsigned short* wnh = (unsigned short*)(ws + WS_WNH);
  unsigned short* wnl = (unsigned short*)(ws + WS_WNL);

  // 2 dispatches total; normalize kernel zeroes counts/sse/done (stream-ordered
  // before the mega kernel; ws is re-poisoned 0xAA before every call).
  normalize_w_kernel<<<KCODES, 64, 0, stream>>>(w, wn, sk, wnh, wnl,
                                                counts, sse_accum, done);
  vq_mega_kernel<<<NBLOCKS, 256, 0, stream>>>(
      x, wnh, wnl, sk, wn, out, counts, sse_accum, done);
}

// Round 9
// 129.955 us; speedup vs baseline: 1.2084x; 1.2084x over previous
//
#include <hip/hip_runtime.h>
#include <hip/hip_bf16.h>
#include <math.h>

// Problem constants (fixed by the reference)
#define NROWS   65536          // 16*4096 flattened rows
#define DIM     64             // embedding dim
#define KCODES  1024           // num embeddings
#define RPB     128            // rows per block (best measured staging amortization)
#define NBLOCKS (NROWS / RPB)  // 512 mega-kernel blocks

// Tier threshold in quantized-key bins. Keys truncate dist4 to 64-ulp bins:
// bin = 1.5e-5 (dist4 in [2,4)) or 3.05e-5 ([4,8)). Guarantee uses the SMALL
// bin: gap >= (NEXACT-1)*1.5e-5 = 1.2e-4 >= 2*err for err <= 6e-5 (paranoid;
// realistic split-2 error ~1e-5).
//   b2-b1 >= NEXACT              -> i1 provably exact
//   else if b3-b1 >= NEXACT      -> true argmin in {i1,i2}: 2-cand refine
//   else                         -> full exact scan (rare)
#define NEXACT 9u

typedef short short8 __attribute__((ext_vector_type(8)));   // 8 bf16 = 4 VGPR (MFMA A/B frag)
typedef float f32x4  __attribute__((ext_vector_type(4)));   // MFMA C/D frag

// Output layout (floats), reference return order:
//   out[0] loss | out[1..] quantized (N*D) | perplexity | indices (as float)
#define OUT_Q_OFF    ((size_t)1)
#define OUT_PERP_OFF ((size_t)(1 + (size_t)NROWS * DIM))
#define OUT_IDX_OFF  ((size_t)(2 + (size_t)NROWS * DIM))

// Workspace layout (bytes); zeroing done by normalize_w_kernel (stream-ordered)
#define WS_COUNTS 0                         // unsigned[1024]
#define WS_SSEC   4096                      // float   (global SSE accumulator)
#define WS_DONE   4100                      // unsigned (blocks-done counter)
#define WS_WN     8192                      // float wn[1024*64]
#define WS_SK     (WS_WN + KCODES*DIM*4)    // float sk[1024]
#define WS_WNH    (WS_SK + KCODES*4)        // ushort wnh[1024*64]
#define WS_WNL    (WS_WNH + KCODES*DIM*2)   // ushort wnl[1024*64]

__device__ __forceinline__ unsigned short bf16_rne(float f) {
  unsigned u = __float_as_uint(f);
  return (unsigned short)((u + 0x7FFFu + ((u >> 16) & 1u)) >> 16);
}
__device__ __forceinline__ float bf16f(unsigned short h) {
  return __uint_as_float(((unsigned)h) << 16);
}
__device__ __forceinline__ unsigned med3u(unsigned a, unsigned b, unsigned c) {
  unsigned d;
  asm("v_med3_u32 %0, %1, %2, %3" : "=v"(d) : "v"(a), "v"(b), "v"(c));
  return d;
}

// Normalize codebook + split to bf16 hi/lo + zero the mega-kernel's counters.
__global__ void __launch_bounds__(64) normalize_w_kernel(
    const float* __restrict__ w, float* __restrict__ wn, float* __restrict__ sk,
    unsigned short* __restrict__ wnh, unsigned short* __restrict__ wnl,
    unsigned* __restrict__ counts, float* __restrict__ sse_accum,
    unsigned* __restrict__ done) {
  const int k = blockIdx.x;   // one code per 64-lane wave
  const int d = threadIdx.x;
  if (d == 0) {
    counts[k] = 0u;                                   // 1024 blocks cover counts[1024]
    if (k == 0) { *sse_accum = 0.f; *done = 0u; }
  }
  float v = w[k * DIM + d];
  float ss = v * v;
  #pragma unroll
  for (int o = 32; o > 0; o >>= 1) ss += __shfl_xor(ss, o, 64);
  const float den = fmaxf(sqrtf(ss), 1e-12f);
  const float q = v / den;                 // true division: hug reference rounding
  wn[k * DIM + d] = q;
  const unsigned short h = bf16_rne(q);
  wnh[k * DIM + d] = h;
  wnl[k * DIM + d] = bf16_rne(q - bf16f(h));
  float s2 = q * q;
  #pragma unroll
  for (int o = 32; o > 0; o >>= 1) s2 += __shfl_xor(s2, o, 64);
  if (d == 0) sk[k] = s2;
}

// Mega-kernel: split-2 bf16 MFMA filter with packed-key top-3 (codes embedded,
// 6-bit per-lane residue trick) + tiered refine + bookkeeping + finalize.
// Block = 256 thr (4 waves) = 128 rows (2 16-row MFMA tiles per wave).
__global__ void __launch_bounds__(256) vq_mega_kernel(
    const float* __restrict__ x, const unsigned short* __restrict__ wnh,
    const unsigned short* __restrict__ wnl, const float* __restrict__ sk,
    const float* __restrict__ wn, float* __restrict__ out,
    unsigned* __restrict__ counts, float* __restrict__ sse_accum,
    unsigned* __restrict__ done) {
  // AB union: phase A: Ah=[0,4608) Al=[4608,9216) u32 (128 rows x 36 u32)
  //           phase B: buf b at b*4608: Bh=[+0,+2304) Bl=[+2304,+4608)
  __shared__ unsigned AB[9216];
  __shared__ float skb[2][64];     // staged sk + 4.0 per chunk
  __shared__ float c_arr[RPB];     // ||xn||^2 per row
  __shared__ float rowsse[RPB];    // per-row SSE (filter-approx; exact if refined)
  __shared__ int   ib[RPB];        // per-row final idx
  __shared__ int   qlist[RPB];     // 2-candidate queue: rl | i1<<7 | i2<<17
  __shared__ int   flist[RPB];     // full-scan queue: row_local
  __shared__ int   qn_s, fn_s;
  __shared__ int   islast;
  const int tid = threadIdx.x;
  const int lane = tid & 63, wave = tid >> 6;

  if (tid == 0) { qn_s = 0; fn_s = 0; }

  // ---- phase 1: 2 threads per row: normalize + split to bf16 hi/lo ----
  {
    const int row_l = tid >> 1;               // 0..127
    const int half = tid & 1;                 // halves of the row (8 float4 each)
    const size_t row = (size_t)blockIdx.x * RPB + row_l;
    const float4* xr = (const float4*)(x + row * DIM) + half * 8;
    float4 xv[8];
    float ss = 0.f;
    #pragma unroll
    for (int i = 0; i < 8; i++) {
      xv[i] = xr[i];
      ss += xv[i].x * xv[i].x + xv[i].y * xv[i].y + xv[i].z * xv[i].z + xv[i].w * xv[i].w;
    }
    ss += __shfl_xor(ss, 1, 64);                                // 2-lane row group
    const float inv = 1.0f / fmaxf(sqrtf(ss), 1e-12f);          // filter-only normalize
    float c = 0.f;
    #pragma unroll
    for (int i = 0; i < 8; i++) {
      const float a0 = xv[i].x * inv, a1 = xv[i].y * inv;
      const float a2 = xv[i].z * inv, a3 = xv[i].w * inv;
      c += a0 * a0 + a1 * a1 + a2 * a2 + a3 * a3;
      const unsigned short h0 = bf16_rne(a0), h1 = bf16_rne(a1);
      const unsigned short h2 = bf16_rne(a2), h3 = bf16_rne(a3);
      const unsigned short l0 = bf16_rne(a0 - bf16f(h0)), l1 = bf16_rne(a1 - bf16f(h1));
      const unsigned short l2 = bf16_rne(a2 - bf16f(h2)), l3 = bf16_rne(a3 - bf16f(h3));
      AB[row_l * 36 + half * 16 + 2 * i]            = (unsigned)h0 | ((unsigned)h1 << 16);
      AB[row_l * 36 + half * 16 + 2 * i + 1]        = (unsigned)h2 | ((unsigned)h3 << 16);
      AB[4608 + row_l * 36 + half * 16 + 2 * i]     = (unsigned)l0 | ((unsigned)l1 << 16);
      AB[4608 + row_l * 36 + half * 16 + 2 * i + 1] = (unsigned)l2 | ((unsigned)l3 << 16);
    }
    c += __shfl_xor(c, 1, 64);
    if (half == 0) c_arr[row_l] = c;
  }
  __syncthreads();

  // ---- A fragments -> registers (A[m=lane&15][k=(lane>>4)*8+j]) ----
  short8 ah[2][2], al[2][2];
  #pragma unroll
  for (int rt = 0; rt < 2; rt++)
    #pragma unroll
    for (int kk = 0; kk < 2; kk++) {
      const int r = wave * 32 + rt * 16 + (lane & 15);
      ah[rt][kk] = *(const short8*)&AB[r * 36 + kk * 16 + (lane >> 4) * 4];
      al[rt][kk] = *(const short8*)&AB[4608 + r * 36 + kk * 16 + (lane >> 4) * 4];
    }
  __syncthreads();   // A region now dead -> becomes B double-buffer

  // per-slot packed-key top-3 (k1<=k2<=k3). Key = (fp32bits(dist4) & ~63) | chi
  // where chi = code>>4 (6 bits); code low 4 bits == lane&15 (implicit).
  unsigned k1[8], k2[8], k3[8];
  #pragma unroll
  for (int s = 0; s < 8; s++) { k1[s] = 0xFFFFFFFFu; k2[s] = 0xFFFFFFFFu; k3[s] = 0xFFFFFFFFu; }

  // stage chunk 0 into buf 0
  {
    const int code = tid >> 2, q = tid & 3;
    const float4* gh = (const float4*)(wnh + (size_t)code * DIM + q * 16);
    const float4* gl = (const float4*)(wnl + (size_t)code * DIM + q * 16);
    float4* dh = (float4*)&AB[code * 36 + q * 8];
    float4* dl = (float4*)&AB[2304 + code * 36 + q * 8];
    dh[0] = gh[0]; dh[1] = gh[1];
    dl[0] = gl[0]; dl[1] = gl[1];
    if (tid < 64) skb[0][tid] = sk[tid] + 4.0f;
  }

  #pragma unroll 2
  for (int c = 0; c < 16; c++) {
    const int b = c & 1;
    __syncthreads();   // buf b fully staged; buf b^1 free to overwrite
    if (c < 15) {      // stage next chunk (loads fly during compute below)
      const int nb = b ^ 1;
      const int code = tid >> 2, q = tid & 3;
      const float4* gh = (const float4*)(wnh + (size_t)((c + 1) * 64 + code) * DIM + q * 16);
      const float4* gl = (const float4*)(wnl + (size_t)((c + 1) * 64 + code) * DIM + q * 16);
      float4* dh = (float4*)&AB[nb * 4608 + code * 36 + q * 8];
      float4* dl = (float4*)&AB[nb * 4608 + 2304 + code * 36 + q * 8];
      dh[0] = gh[0]; dh[1] = gh[1];
      dl[0] = gl[0]; dl[1] = gl[1];
      if (tid < 64) skb[nb][tid] = sk[(c + 1) * 64 + tid] + 4.0f;
    }
    #pragma unroll
    for (int tt = 0; tt < 4; tt++) {
      const int cb = tt * 16 + (lane & 15);       // code within chunk (B col)
      const float skv4 = skb[b][cb];
      const unsigned chi = (unsigned)(c * 4 + tt); // code >> 4 (wave-uniform)
      const short8 bh0 = *(const short8*)&AB[b * 4608 + cb * 36 + 0 * 16 + (lane >> 4) * 4];
      const short8 bh1 = *(const short8*)&AB[b * 4608 + cb * 36 + 1 * 16 + (lane >> 4) * 4];
      const short8 bl0 = *(const short8*)&AB[b * 4608 + 2304 + cb * 36 + 0 * 16 + (lane >> 4) * 4];
      const short8 bl1 = *(const short8*)&AB[b * 4608 + 2304 + cb * 36 + 1 * 16 + (lane >> 4) * 4];
      #pragma unroll
      for (int rt = 0; rt < 2; rt++) {
        f32x4 acc = {0.f, 0.f, 0.f, 0.f};
        acc = __builtin_amdgcn_mfma_f32_16x16x32_bf16(ah[rt][0], bh0, acc, 0, 0, 0);
        acc = __builtin_amdgcn_mfma_f32_16x16x32_bf16(ah[rt][1], bh1, acc, 0, 0, 0);
        acc = __builtin_amdgcn_mfma_f32_16x16x32_bf16(al[rt][0], bh0, acc, 0, 0, 0);
        acc = __builtin_amdgcn_mfma_f32_16x16x32_bf16(al[rt][1], bh1, acc, 0, 0, 0);
        acc = __builtin_amdgcn_mfma_f32_16x16x32_bf16(ah[rt][0], bl0, acc, 0, 0, 0);
        acc = __builtin_amdgcn_mfma_f32_16x16x32_bf16(ah[rt][1], bl1, acc, 0, 0, 0);
        #pragma unroll
        for (int i = 0; i < 4; i++) {   // C layout: col=lane&15(code), row=(lane>>4)*4+i
          const float dist4 = fmaf(-2.0f, acc[i], skv4);            // sk+4-2dot in (2.98,7.02)
          const unsigned key = (__float_as_uint(dist4) & 0xFFFFFFC0u) | chi;
          const int s = rt * 4 + i;
          const unsigned t = (k1[s] > key) ? k1[s] : key;           // max
          k3[s] = med3u(k2[s], k3[s], t);
          k2[s] = med3u(k1[s], k2[s], key);
          k1[s] = (key < k1[s]) ? key : k1[s];                      // min
        }
      }
    }
  }

  // ---- per-row top-3 reduce across the 16 lanes of each group ----
  #pragma unroll
  for (int s = 0; s < 8; s++) {
    // expand: dist4 has constant top-4 fp32 bits ('0100') -> <<4 keeps order;
    // low 10 bits become the full code (chi*16 + lane&15).
    unsigned a1 = (k1[s] << 4) | (unsigned)(lane & 15);
    unsigned a2 = (k2[s] << 4) | (unsigned)(lane & 15);
    unsigned a3 = (k3[s] << 4) | (unsigned)(lane & 15);
    #pragma unroll
    for (int m = 1; m < 16; m <<= 1) {
      const unsigned p1 = (unsigned)__shfl_xor((int)a1, m, 64);
      const unsigned p2 = (unsigned)__shfl_xor((int)a2, m, 64);
      const unsigned p3 = (unsigned)__shfl_xor((int)a3, m, 64);
      const unsigned th = (a1 > p1) ? a1 : p1;
      const unsigned n1 = (a1 < p1) ? a1 : p1;
      const unsigned m2 = (a2 < p2) ? a2 : p2;
      const unsigned m3 = (a3 < p3) ? a3 : p3;
      const unsigned hi = (th > m2) ? th : m2;
      a1 = n1;
      a2 = (th < m2) ? th : m2;
      const unsigned md = med3u(th, m2, m3);
      a3 = (hi < md) ? hi : md;
    }
    if ((lane & 15) == 0) {
      const int row_local = wave * 32 + (s >> 2) * 16 + (lane >> 4) * 4 + (s & 3);
      const int i1 = (int)(a1 & 1023u);
      ib[row_local] = i1;
      // approx SSE from quantized dist (reconstruct fp32 bits; +half-bin)
      const unsigned ub = ((a1 & 0xFFFFFC00u) >> 4) | 0x40000000u;
      rowsse[row_local] = __uint_as_float(ub) - 4.0f + c_arr[row_local] + 1.6e-5f;
      const unsigned b1 = a1 >> 10, b2 = a2 >> 10, b3 = a3 >> 10;
      if (b3 - b1 < NEXACT) {                        // 3rd contender too close
        flist[atomicAdd(&fn_s, 1)] = row_local;
      } else if (b2 - b1 < NEXACT) {                 // argmin provably in {i1,i2}
        qlist[atomicAdd(&qn_s, 1)] = row_local | (i1 << 7) | ((int)(a2 & 1023u) << 17);
      }
    }
  }
  __syncthreads();

  // ---- tier 1: 2-candidate exact refine, one THREAD per queued row ----
  const int qn = qn_s, fn = fn_s;
  if (tid < qn) {
    const int packed = qlist[tid];
    const int rl = packed & 127;
    const int c1 = (packed >> 7) & 1023, c2i = (packed >> 17) & 1023;
    const size_t row = (size_t)blockIdx.x * RPB + rl;
    const float4* xr = (const float4*)(x + row * DIM);
    float4 xv[16];
    float ss = 0.f;
    #pragma unroll
    for (int i = 0; i < 16; i++) {              // canonical serial order
      xv[i] = xr[i];
      ss += xv[i].x * xv[i].x + xv[i].y * xv[i].y + xv[i].z * xv[i].z + xv[i].w * xv[i].w;
    }
    const float den = fmaxf(sqrtf(ss), 1e-12f);
    #pragma unroll
    for (int i = 0; i < 16; i++) { xv[i].x /= den; xv[i].y /= den; xv[i].z /= den; xv[i].w /= den; }
    float cc = 0.f;
    #pragma unroll
    for (int i = 0; i < 16; i++)
      cc += xv[i].x * xv[i].x + xv[i].y * xv[i].y + xv[i].z * xv[i].z + xv[i].w * xv[i].w;
    float dd[2]; const int cand[2] = {c1, c2i};
    #pragma unroll
    for (int t = 0; t < 2; t++) {
      const float4* wr = (const float4*)(wn + (size_t)cand[t] * DIM);
      float e0 = 0.f, e1 = 0.f, e2 = 0.f, e3 = 0.f;
      #pragma unroll
      for (int i = 0; i < 16; i++) {
        const float4 wv = wr[i];
        e0 = fmaf(xv[i].x, wv.x, e0);
        e1 = fmaf(xv[i].y, wv.y, e1);
        e2 = fmaf(xv[i].z, wv.z, e2);
        e3 = fmaf(xv[i].w, wv.w, e3);
      }
      dd[t] = (cc + sk[cand[t]]) - 2.0f * ((e0 + e1) + (e2 + e3));
    }
    const bool tb = (dd[1] < dd[0]) || (dd[1] == dd[0] && c2i < c1);
    ib[rl] = tb ? c2i : c1;
    rowsse[rl] = tb ? dd[1] : dd[0];
  }

  // ---- tier 2: full exact scan, one WAVE per row (rare) ----
  for (int qi = wave; qi < fn; qi += 4) {
    const int rl = flist[qi];
    const size_t row = (size_t)blockIdx.x * RPB + rl;
    const float4* xr = (const float4*)(x + row * DIM);
    float4 xv[16];
    float ss = 0.f;
    #pragma unroll
    for (int i = 0; i < 16; i++) {
      xv[i] = xr[i];
      ss += xv[i].x * xv[i].x + xv[i].y * xv[i].y + xv[i].z * xv[i].z + xv[i].w * xv[i].w;
    }
    const float den = fmaxf(sqrtf(ss), 1e-12f);
    #pragma unroll
    for (int i = 0; i < 16; i++) { xv[i].x /= den; xv[i].y /= den; xv[i].z /= den; xv[i].w /= den; }
    float cc = 0.f;
    #pragma unroll
    for (int i = 0; i < 16; i++)
      cc += xv[i].x * xv[i].x + xv[i].y * xv[i].y + xv[i].z * xv[i].z + xv[i].w * xv[i].w;

    float best = INFINITY;
    int bidx = 0x7FFFFFFF;
    for (int j = 0; j < 16; j++) {
      const int k = j * 64 + lane;
      const float4* wr = (const float4*)(wn + (size_t)k * DIM);
      float e0 = 0.f, e1 = 0.f, e2 = 0.f, e3 = 0.f;
      #pragma unroll
      for (int i = 0; i < 16; i++) {
        const float4 wv = wr[i];
        e0 = fmaf(xv[i].x, wv.x, e0);
        e1 = fmaf(xv[i].y, wv.y, e1);
        e2 = fmaf(xv[i].z, wv.z, e2);
        e3 = fmaf(xv[i].w, wv.w, e3);
      }
      const float dot = (e0 + e1) + (e2 + e3);
      const float dist = (cc + sk[k]) - 2.0f * dot;
      if (dist < best) { best = dist; bidx = k; }   // per-lane ascending k
    }
    #pragma unroll
    for (int m = 1; m < 64; m <<= 1) {
      const float pb = __shfl_xor(best, m, 64);
      const int pi = __shfl_xor(bidx, m, 64);
      if (pb < best || (pb == best && pi < bidx)) { best = pb; bidx = pi; }  // first-occurrence
    }
    if (lane == 0) { ib[rl] = bidx; rowsse[rl] = best; }
  }
  __syncthreads();

  // ---- bookkeeping with FINAL indices ----
  if (tid < RPB) {
    const size_t row = (size_t)blockIdx.x * RPB + tid;
    const int idx = ib[tid];
    out[OUT_IDX_OFF + row] = (float)idx;
    atomicAdd(&counts[idx], 1u);
  }

  // quantized write: 128 rows x 64 elems; per wave-iter one wn row (broadcast)
  const size_t obase = OUT_Q_OFF + (size_t)blockIdx.x * (RPB * DIM);
  #pragma unroll 4
  for (int j = 0; j < 32; j++) {
    const int e = j * 256 + tid;           // e>>6 wave-uniform
    out[obase + e] = wn[(size_t)ib[e >> 6] * DIM + (e & 63)];
  }

  // block SSE reduction -> one global atomic
  __syncthreads();
  for (int s = 64; s > 0; s >>= 1) {
    if (tid < s) rowsse[tid] += rowsse[tid + s];
    __syncthreads();
  }
  if (tid == 0) atomicAdd(sse_accum, rowsse[0]);

  // ---- last-block-done finalize ----
  if (tid == 0) {
    __threadfence();                          // release: counts/sse visible device-wide
    islast = (atomicAdd(done, 1u) == NBLOCKS - 1) ? 1 : 0;
  }
  __syncthreads();
  if (islast) {
    __threadfence();                          // acquire side
    float h = 0.f;
    #pragma unroll
    for (int i = 0; i < 4; i++) {
      const float cv = (float)counts[tid * 4 + i];
      const float avg = cv * (1.0f / (float)NROWS);
      h += avg * logf(avg + 1e-10f);
    }
    #pragma unroll
    for (int o = 32; o > 0; o >>= 1) h += __shfl_xor(h, o, 64);
    __shared__ float hred[4];
    if (lane == 0) hred[wave] = h;
    __syncthreads();
    if (tid == 0) {
      const float H = -(hred[0] + hred[1] + hred[2] + hred[3]);
      const float mse = *sse_accum * (1.0f / (float)((size_t)NROWS * DIM));
      out[0] = mse + 0.25f * mse;             // == 1.25*mse in fp32
      out[OUT_PERP_OFF] = expf(H);
    }
  }
}

extern "C" void kernel_launch(void* const* d_in, const int* in_sizes, int n_in,
                              void* d_out, int out_size, void* d_ws, size_t ws_size,
                              hipStream_t stream) {
  const float* x = (const float*)d_in[0];   // [16,4096,64] fp32
  const float* w = (const float*)d_in[1];   // [1024,64] fp32
  float* out = (float*)d_out;

  char* ws = (char*)d_ws;
  unsigned* counts    = (unsigned*)(ws + WS_COUNTS);
  float* sse_accum    = (float*)(ws + WS_SSEC);
  unsigned* done      = (unsigned*)(ws + WS_DONE);
  float* wn           = (float*)(ws + WS_WN);
  float* sk           = (float*)(ws + WS_SK);
  unsigned short* wnh = (unsigned short*)(ws + WS_WNH);
  unsigned short* wnl = (unsigned short*)(ws + WS_WNL);

  // 2 dispatches total; normalize kernel zeroes counts/sse/done (stream-ordered
  // before the mega kernel; ws is re-poisoned 0xAA before every call).
  normalize_w_kernel<<<KCODES, 64, 0, stream>>>(w, wn, sk, wnh, wnl,
                                                counts, sse_accum, done);
  vq_mega_kernel<<<NBLOCKS, 256, 0, stream>>>(
      x, wnh, wnl, sk, wn, out, counts, sse_accum, done);
}